// Round 1
// baseline (34.569 us; speedup 1.0000x reference)
//
#include <hip/hip_runtime.h>

// Conv2d 3x3 pad1: x(2,64,112,112) f32, w(64,64,3,3) f32, bias(64) f32 -> out(2,64,112,112) f32
// Strategy: pre-transform to padded NHWC bf16 + [tap][oc][ic] bf16 weights,
// then implicit-GEMM on mfma_f32_16x16x32_bf16 with direct global fragment loads.

#define IN_C  64
#define OUT_C 64
#define BN    2
#define HH    112
#define WW    112
#define HP    114
#define WP    114

typedef __attribute__((ext_vector_type(8))) short          bf16x8;
typedef __attribute__((ext_vector_type(8))) unsigned short u16x8;
typedef __attribute__((ext_vector_type(4))) float          f32x4;

static __device__ __forceinline__ unsigned short f2bf(float f) {
    unsigned int u = __builtin_bit_cast(unsigned int, f);
    u += 0x7FFFu + ((u >> 16) & 1u);   // round-nearest-even
    return (unsigned short)(u >> 16);
}

// x (B,64,112,112) f32  ->  xt (B,114,114,64) bf16, zero halo.
// One block per (b, yp) padded row; thread = xp. Reads are wave-coalesced
// (consecutive xp -> consecutive float addresses per channel iteration).
__global__ __launch_bounds__(128) void prep_x(const float* __restrict__ x,
                                              unsigned short* __restrict__ xt) {
    int xp = threadIdx.x;
    if (xp >= WP) return;
    int b  = blockIdx.x / HP;
    int yp = blockIdx.x % HP;
    unsigned short* dst = xt + (((size_t)b * HP + yp) * WP + xp) * IN_C;
    bool border = (yp == 0) | (yp == HP - 1) | (xp == 0) | (xp == WP - 1);
    if (border) {
        u16x8 z = {0, 0, 0, 0, 0, 0, 0, 0};
#pragma unroll
        for (int c0 = 0; c0 < IN_C; c0 += 8)
            *reinterpret_cast<u16x8*>(dst + c0) = z;
        return;
    }
    const float* src = x + ((size_t)b * IN_C * HH + (yp - 1)) * WW + (xp - 1);
#pragma unroll
    for (int c0 = 0; c0 < IN_C; c0 += 8) {
        u16x8 v;
#pragma unroll
        for (int j = 0; j < 8; ++j)
            v[j] = f2bf(src[(size_t)(c0 + j) * (HH * WW)]);
        *reinterpret_cast<u16x8*>(dst + c0) = v;
    }
}

// w (64,64,3,3) f32 -> wt[tap][oc][ic] bf16 (tap = r*3+s). 4096 threads.
__global__ __launch_bounds__(256) void prep_w(const float* __restrict__ w,
                                              unsigned short* __restrict__ wt) {
    int g  = blockIdx.x * 256 + threadIdx.x;      // 0..4095 = oc*64+ic
    int oc = g >> 6, ic = g & 63;
    const float* src = w + (size_t)g * 9;         // (oc,ic) block of 9 contiguous
#pragma unroll
    for (int t = 0; t < 9; ++t)
        wt[(size_t)t * (OUT_C * IN_C) + oc * IN_C + ic] = f2bf(src[t]);
}

// Implicit GEMM: M=16 pixels/wave (one row segment), N=64 oc (4 frags), K=576.
// A frag: lane holds xt[b][y+r][x0+(l&15)+s][icc*32 + 8*(l>>4) .. +7]  (16B load)
// B frag: lane holds wt[tap][f*16+(l&15)][icc*32 + 8*(l>>4) .. +7]     (16B load)
// D: col(oc-in-frag)=l&15, row(pixel)=4*(l>>4)+reg  [m89-verified layout]
__global__ __launch_bounds__(256) void conv_mfma(const unsigned short* __restrict__ xt,
                                                 const unsigned short* __restrict__ wt,
                                                 const float* __restrict__ bias,
                                                 float* __restrict__ out) {
    int tid = threadIdx.x;
    int l   = tid & 63;
    int wv  = tid >> 6;                 // wave 0..3 -> row within ytile
    int blk = blockIdx.x;
    int b   = blk / 196;
    int rm  = blk % 196;
    int ytile = rm / 7, xtile = rm % 7;
    int y  = ytile * 4 + wv;            // output row, 0..111
    int x0 = xtile * 16;                // output col base, 0..96
    int lm = l & 15;                    // pixel-in-frag (A) / oc-in-frag (B,D)
    int lk = l >> 4;                    // k-block 0..3

    f32x4 acc0 = {0.f, 0.f, 0.f, 0.f};
    f32x4 acc1 = {0.f, 0.f, 0.f, 0.f};
    f32x4 acc2 = {0.f, 0.f, 0.f, 0.f};
    f32x4 acc3 = {0.f, 0.f, 0.f, 0.f};

    // padded coords: output (y,x) tap (r,s) reads xt row y+r, col x+s
    const unsigned short* xb = xt + (((size_t)b * HP + y) * WP + x0 + lm) * IN_C + lk * 8;

#pragma unroll
    for (int r = 0; r < 3; ++r) {
#pragma unroll
        for (int s = 0; s < 3; ++s) {
            const unsigned short* xp = xb + (r * WP + s) * IN_C;
            const unsigned short* wp = wt + (((r * 3 + s) * OUT_C) + lm) * IN_C + lk * 8;
#pragma unroll
            for (int icc = 0; icc < 2; ++icc) {
                bf16x8 a  = *reinterpret_cast<const bf16x8*>(xp + icc * 32);
                bf16x8 b0 = *reinterpret_cast<const bf16x8*>(wp + icc * 32);
                bf16x8 b1 = *reinterpret_cast<const bf16x8*>(wp + 16 * IN_C + icc * 32);
                bf16x8 b2 = *reinterpret_cast<const bf16x8*>(wp + 32 * IN_C + icc * 32);
                bf16x8 b3 = *reinterpret_cast<const bf16x8*>(wp + 48 * IN_C + icc * 32);
                acc0 = __builtin_amdgcn_mfma_f32_16x16x32_bf16(a, b0, acc0, 0, 0, 0);
                acc1 = __builtin_amdgcn_mfma_f32_16x16x32_bf16(a, b1, acc1, 0, 0, 0);
                acc2 = __builtin_amdgcn_mfma_f32_16x16x32_bf16(a, b2, acc2, 0, 0, 0);
                acc3 = __builtin_amdgcn_mfma_f32_16x16x32_bf16(a, b3, acc3, 0, 0, 0);
            }
        }
    }

    // Epilogue: lane l holds pixels x0+4*lk..+3 for oc = f*16+lm.
    f32x4 accs[4] = {acc0, acc1, acc2, acc3};
    int px = x0 + lk * 4;
#pragma unroll
    for (int f = 0; f < 4; ++f) {
        int oc   = f * 16 + lm;
        float bv = bias[oc];
        f32x4 v  = accs[f];
        v.x += bv; v.y += bv; v.z += bv; v.w += bv;
        *reinterpret_cast<f32x4*>(out + (((size_t)b * OUT_C + oc) * HH + y) * WW + px) = v;
    }
}

extern "C" void kernel_launch(void* const* d_in, const int* in_sizes, int n_in,
                              void* d_out, int out_size, void* d_ws, size_t ws_size,
                              hipStream_t stream) {
    const float* x    = (const float*)d_in[0];
    const float* w    = (const float*)d_in[1];
    const float* bias = (const float*)d_in[2];
    float* out        = (float*)d_out;

    unsigned short* xt = (unsigned short*)d_ws;                    // 2*114*114*64 bf16 = 3,326,976 B
    unsigned short* wt = xt + (size_t)BN * HP * WP * IN_C;         // 9*64*64 bf16 = 73,728 B

    prep_x<<<dim3(BN * HP), dim3(128), 0, stream>>>(x, xt);
    prep_w<<<dim3(16), dim3(256), 0, stream>>>(w, wt);
    conv_mfma<<<dim3(392), dim3(256), 0, stream>>>(xt, wt, bias, out);
}